// Round 6
// baseline (207.409 us; speedup 1.0000x reference)
//
#include <hip/hip_runtime.h>
#include <hip/hip_bf16.h>
#include <stdint.h>

// exp(s/sqrt(128)) = exp2(s * log2(e)/sqrt(128)); folded into Q at k_qk epilogue
#define SCALE_LOG2E 0.12751743f

typedef __bf16 bf16x8 __attribute__((ext_vector_type(8)));
typedef float floatx4 __attribute__((ext_vector_type(4)));
typedef uint32_t u32x4v __attribute__((ext_vector_type(4)));

__device__ __forceinline__ bf16x8 load_bf8(const void* p) {
    u32x4v v = *(const u32x4v*)p;
    return __builtin_bit_cast(bf16x8, v);
}

__device__ __forceinline__ bf16x8 cvt8(float4 u, float4 v) {
    union { bf16x8 v8; __hip_bfloat16 h[8]; } r;
    r.h[0] = __float2bfloat16(u.x); r.h[1] = __float2bfloat16(u.y);
    r.h[2] = __float2bfloat16(u.z); r.h[3] = __float2bfloat16(u.w);
    r.h[4] = __float2bfloat16(v.x); r.h[5] = __float2bfloat16(v.y);
    r.h[6] = __float2bfloat16(v.z); r.h[7] = __float2bfloat16(v.w);
    return r.v8;
}

// async 16B global -> LDS DMA (no VGPR destination; compiler cannot collapse)
__device__ __forceinline__ void dma16(const void* g, void* l) {
    __builtin_amdgcn_global_load_lds(
        (const __attribute__((address_space(1))) uint32_t*)g,
        (__attribute__((address_space(3))) uint32_t*)l, 16, 0, 0);
}

// ---------------------------------------------------------------------------
// Kernel A: cvt w_q,w_k -> bf16 (b<96); c[768] = w_o @ w_v (b 96..98);
// zero num/den/cnt (b 99..131; 16448 contiguous floats in ws: num 8192,
// den 8192, cnt 64).
// ---------------------------------------------------------------------------
__global__ void k_prep(const float* __restrict__ w_q, const float* __restrict__ w_k,
                       const float* __restrict__ w_v, const float* __restrict__ w_o,
                       __hip_bfloat16* __restrict__ wq_bf,
                       __hip_bfloat16* __restrict__ wk_bf,
                       float* __restrict__ c_out,
                       float* __restrict__ numden) {
    int b = blockIdx.x;
    int t = threadIdx.x;
    if (b < 96) {
        #pragma unroll
        for (int p = 0; p < 8; ++p) {
            int i = b * 2048 + p * 256 + t;
            if (i < 98304) wq_bf[i] = __float2bfloat16(w_q[i]);
            else           wk_bf[i - 98304] = __float2bfloat16(w_k[i - 98304]);
        }
    } else if (b < 99) {
        int j = (b - 96) * 256 + t;
        float acc = 0.f;
        #pragma unroll 8
        for (int k = 0; k < 64; ++k) acc += w_o[k] * w_v[k * 768 + j];
        c_out[j] = acc;
    } else {
        int z = (b - 99) * 512 + t * 2;
        if (z < 16448) { numden[z] = 0.f; numden[z + 1] = 0.f; }
    }
}

// ---------------------------------------------------------------------------
// Kernel B (unchanged from R5 — control variable): Q = x1 @ w_q^T * SCALE
// (bid 0..255), K = x2 @ w_k^T (256..511), vs = x2 . c (bid 512..767).
// m97-style global_load_lds double-buffered A-tile, XOR-swizzled chunks.
// ---------------------------------------------------------------------------
__global__ __launch_bounds__(256, 4) void k_qk(
        const float* __restrict__ x1, const float* __restrict__ x2,
        const __hip_bfloat16* __restrict__ wq_bf,
        const __hip_bfloat16* __restrict__ wk_bf,
        const float* __restrict__ c_in,
        __hip_bfloat16* __restrict__ Qb, __hip_bfloat16* __restrict__ Kb,
        float* __restrict__ vs_g) {
    __shared__ alignas(16) float sA[2][32 * 128];  // 2 x 16 KB, swizzled 16B chunks

    int bid = blockIdx.x;
    int t = threadIdx.x;

    if (bid >= 512) {
        // ---- vs blocks: 256 blocks x 32 rows, 8 threads per row ----
        int vb = bid - 512;
        int r = vb * 32 + (t >> 3), h = t & 7;
        const float* xr = x2 + (size_t)r * 768 + h * 96;
        const float* cr = c_in + h * 96;
        float vacc = 0.f;
        #pragma unroll 6
        for (int j = 0; j < 96; j += 4) {
            float4 v = *(const float4*)(xr + j);
            vacc += v.x * cr[j] + v.y * cr[j + 1] + v.z * cr[j + 2] + v.w * cr[j + 3];
        }
        vacc += __shfl_xor(vacc, 1, 64);
        vacc += __shfl_xor(vacc, 2, 64);
        vacc += __shfl_xor(vacc, 4, 64);
        if (h == 0) vs_g[r] = vacc;
        return;
    }

    bool isK = bid >= 256;
    int row0 = (bid & 255) * 32;
    const float* x = isK ? x2 : x1;
    const __hip_bfloat16* w = isK ? wk_bf : wq_bf;
    __hip_bfloat16* outp = isK ? Kb : Qb;

    int wave = t >> 6, lane = t & 63;
    int m = lane & 15, quad = lane >> 4;
    int col0 = wave * 32;

    const float* gsrc[4];
    #pragma unroll
    for (int p = 0; p < 4; ++p) {
        int s = wave * 256 + p * 64 + lane;
        int r = s >> 5, pos = s & 31;
        int c = pos ^ (r & 7);
        gsrc[p] = x + (size_t)(row0 + r) * 768 + c * 4;
    }
    auto dma_tile = [&](int buf, int kc) {
        #pragma unroll
        for (int p = 0; p < 4; ++p)
            dma16(gsrc[p] + kc, &sA[buf][(wave * 256 + p * 64) * 4]);
    };

    const __hip_bfloat16* bp = w + (size_t)(col0 + m) * 768 + quad * 8;

    floatx4 acc[2][2];
    #pragma unroll
    for (int i = 0; i < 2; ++i)
        #pragma unroll
        for (int j = 0; j < 2; ++j) acc[i][j] = {0.f, 0.f, 0.f, 0.f};

    dma_tile(0, 0);

    for (int it = 0; it < 6; ++it) {
        __syncthreads();
        if (it < 5) dma_tile((it + 1) & 1, (it + 1) * 128);

        const float* A = sA[it & 1];
        int kc = it * 128;
        #pragma unroll
        for (int ks = 0; ks < 4; ++ks) {
            bf16x8 afr[2], bfr[2];
            #pragma unroll
            for (int i = 0; i < 2; ++i) {
                int r = i * 16 + m;
                int cb = ks * 8 + quad * 2;
                int p0 = cb ^ (r & 7), p1 = (cb + 1) ^ (r & 7);
                float4 f0 = *(const float4*)&A[r * 128 + p0 * 4];
                float4 f1 = *(const float4*)&A[r * 128 + p1 * 4];
                afr[i] = cvt8(f0, f1);
            }
            #pragma unroll
            for (int j = 0; j < 2; ++j)
                bfr[j] = load_bf8(bp + (size_t)j * 16 * 768 + kc + ks * 32);
            #pragma unroll
            for (int i = 0; i < 2; ++i)
                #pragma unroll
                for (int j = 0; j < 2; ++j)
                    acc[i][j] = __builtin_amdgcn_mfma_f32_16x16x32_bf16(afr[i], bfr[j], acc[i][j], 0, 0, 0);
        }
    }

    float cscale = isK ? 1.0f : SCALE_LOG2E;
    #pragma unroll
    for (int i = 0; i < 2; ++i)
        #pragma unroll
        for (int j = 0; j < 2; ++j)
            #pragma unroll
            for (int r = 0; r < 4; ++r) {
                int row = row0 + i * 16 + quad * 4 + r;
                int col = col0 + j * 16 + m;
                outp[(size_t)row * 128 + col] = __float2bfloat16(acc[i][j][r] * cscale);
            }
}

// ---------------------------------------------------------------------------
// Kernel C: flash-style attention row-sums + fused finalize.
// K tile staged via global_load_lds (dbuf, XOR-swizzled: chunk pos = c^(r&7)),
// ONE barrier per iter. Q-frags in registers. After atomics, the last block
// of each q-group (per-group counter) computes gated = x1*(1-num/den) for its
// 128 rows — k_final fused, one dispatch fewer.
// ---------------------------------------------------------------------------
__global__ __launch_bounds__(256, 2) void k_attn(
        const __hip_bfloat16* __restrict__ Qb, const __hip_bfloat16* __restrict__ Kb,
        const float* __restrict__ vs_g, const float* __restrict__ x1,
        float* __restrict__ num_g, float* __restrict__ den_g,
        int* __restrict__ cnt, float* __restrict__ outp) {
    __shared__ alignas(16) __hip_bfloat16 sK[2][128 * 128];  // 2 x 32 KB swizzled
    __shared__ float sVS[1024];
    __shared__ float sGate[128];
    __shared__ int sOld;

    int bid = blockIdx.x;
    int qb = bid >> 3, tc = bid & 7;
    int q0 = qb * 128, t0 = tc * 1024;

    int t = threadIdx.x;
    int wave = t >> 6, lane = t & 63;
    int wr = wave >> 1, wc = wave & 1;
    int m = lane & 15, quad = lane >> 4;

    // Q fragments (loop-invariant, registers): A[m][k=quad*8+j]
    bf16x8 qf[4][4];
    #pragma unroll
    for (int i = 0; i < 4; ++i)
        #pragma unroll
        for (int kk = 0; kk < 4; ++kk)
            qf[kk][i] = load_bf8(Qb + (size_t)(q0 + wr * 64 + i * 16 + m) * 128 + kk * 32 + quad * 8);

    #pragma unroll
    for (int p = 0; p < 4; ++p) sVS[p * 256 + t] = vs_g[t0 + p * 256 + t];

    // K-tile DMA: tile = 128 rows x 16 chunks(16B). Issue p by wave w covers
    // slots s0=(p*4+w)*64 .. +63; lane's slot s -> r=s>>4, pos=s&15, src chunk
    // c = pos ^ (r&7). dst = wave-uniform base + lane*16 (HW).
    auto dma_tile = [&](int buf, int tbase) {
        #pragma unroll
        for (int p = 0; p < 8; ++p) {
            int s0 = (p * 4 + wave) * 64;
            int r = (p * 4 + wave) * 4 + quad;   // (s0+lane)>>4
            int c = m ^ (r & 7);                 // pos=m
            dma16(Kb + (size_t)(tbase + r) * 128 + c * 8, &sK[buf][(size_t)s0 * 8]);
        }
    };

    dma_tile(0, t0);

    float num_acc[4][4], den_acc[4][4];
    #pragma unroll
    for (int i = 0; i < 4; ++i)
        #pragma unroll
        for (int r = 0; r < 4; ++r) { num_acc[i][r] = 0.f; den_acc[i][r] = 0.f; }

    for (int it = 0; it < 8; ++it) {
        __syncthreads();                 // drains DMA for tile it
        if (it < 7) dma_tile((it + 1) & 1, t0 + (it + 1) * 128);

        const __hip_bfloat16* K = sK[it & 1];

        floatx4 acc[4][4];
        #pragma unroll
        for (int i = 0; i < 4; ++i)
            #pragma unroll
            for (int j = 0; j < 4; ++j) acc[i][j] = {0.f, 0.f, 0.f, 0.f};

        #pragma unroll
        for (int kk = 0; kk < 4; ++kk) {
            bf16x8 bfr[4];
            #pragma unroll
            for (int j = 0; j < 4; ++j) {
                int rB = wc * 64 + j * 16 + m;
                int pos = (kk * 4 + quad) ^ (rB & 7);
                bfr[j] = load_bf8(&K[rB * 128 + pos * 8]);
            }
            #pragma unroll
            for (int i = 0; i < 4; ++i)
                #pragma unroll
                for (int j = 0; j < 4; ++j)
                    acc[i][j] = __builtin_amdgcn_mfma_f32_16x16x32_bf16(qf[kk][i], bfr[j], acc[i][j], 0, 0, 0);
        }

        #pragma unroll
        for (int j = 0; j < 4; ++j) {
            float vsv = sVS[it * 128 + wc * 64 + j * 16 + m];
            #pragma unroll
            for (int i = 0; i < 4; ++i)
                #pragma unroll
                for (int r = 0; r < 4; ++r) {
                    float p = __builtin_amdgcn_exp2f(acc[i][j][r]);
                    den_acc[i][r] += p;
                    num_acc[i][r] += p * vsv;
                }
        }
    }

    #pragma unroll
    for (int i = 0; i < 4; ++i)
        #pragma unroll
        for (int r = 0; r < 4; ++r) {
            float n = num_acc[i][r], d = den_acc[i][r];
            #pragma unroll
            for (int mask = 1; mask <= 8; mask <<= 1) {
                n += __shfl_xor(n, mask, 64);
                d += __shfl_xor(d, mask, 64);
            }
            if ((lane & 15) == 0) {
                int row = q0 + wr * 64 + i * 16 + quad * 4 + r;
                atomicAdd(&num_g[row], n);
                atomicAdd(&den_g[row], d);
            }
        }

    // ---- fused finalize: last t-chunk block of this q-group gates 128 rows ----
    __threadfence();        // release our atomics
    __syncthreads();        // all waves of this block done
    if (t == 0)
        sOld = __hip_atomic_fetch_add(&cnt[qb], 1, __ATOMIC_ACQ_REL, __HIP_MEMORY_SCOPE_AGENT);
    __syncthreads();
    if (sOld == 7) {
        __threadfence();
        if (t < 128) {
            float n = __hip_atomic_load(&num_g[q0 + t], __ATOMIC_RELAXED, __HIP_MEMORY_SCOPE_AGENT);
            float d = __hip_atomic_load(&den_g[q0 + t], __ATOMIC_RELAXED, __HIP_MEMORY_SCOPE_AGENT);
            sGate[t] = 1.0f - n / d;
        }
        __syncthreads();
        const float4* src = (const float4*)(x1 + (size_t)q0 * 768);
        float4* dst = (float4*)(outp + (size_t)q0 * 768);
        #pragma unroll 4
        for (int p = 0; p < 96; ++p) {
            int idx = p * 256 + t;           // 0..24575 float4s (128 rows x 192)
            float g = sGate[idx / 192];
            float4 v = src[idx];
            v.x *= g; v.y *= g; v.z *= g; v.w *= g;
            dst[idx] = v;
        }
    }
}

// ---------------------------------------------------------------------------
extern "C" void kernel_launch(void* const* d_in, const int* in_sizes, int n_in,
                              void* d_out, int out_size, void* d_ws, size_t ws_size,
                              hipStream_t stream) {
    const float* x1  = (const float*)d_in[0];
    const float* x2  = (const float*)d_in[1];
    const float* w_q = (const float*)d_in[2];
    const float* w_k = (const float*)d_in[3];
    const float* w_v = (const float*)d_in[4];
    const float* w_o = (const float*)d_in[5];
    float* outp = (float*)d_out;

    char* ws = (char*)d_ws;
    __hip_bfloat16* wq_bf = (__hip_bfloat16*)(ws + 0);        // 196608 B
    __hip_bfloat16* wk_bf = (__hip_bfloat16*)(ws + 196608);   // 196608 B
    float* c_buf          = (float*)(ws + 393216);            // 3072 B
    __hip_bfloat16* Qb    = (__hip_bfloat16*)(ws + 396288);   // 2 MB
    __hip_bfloat16* Kb    = (__hip_bfloat16*)(ws + 2493440);  // 2 MB
    float* vs_g           = (float*)(ws + 4590592);           // 32 KB
    float* num_g          = (float*)(ws + 4623360);           // 32 KB
    float* den_g          = (float*)(ws + 4656128);           // 32 KB
    int*   cnt            = (int*)  (ws + 4688896);           // 256 B (contig after den)

    k_prep<<<132, 256, 0, stream>>>(w_q, w_k, w_v, w_o, wq_bf, wk_bf, c_buf, num_g);
    k_qk<<<768, 256, 0, stream>>>(x1, x2, wq_bf, wk_bf, c_buf, Qb, Kb, vs_g);
    k_attn<<<512, 256, 0, stream>>>(Qb, Kb, vs_g, x1, num_g, den_g, cnt, outp);
}